// Round 7
// baseline (4418.637 us; speedup 1.0000x reference)
//
#include <hip/hip_runtime.h>
#include <hip/hip_bf16.h>

#define BATCH 8192
#define INPUT 64
#define HIDDEN 512
#define OUTPUT 64
#define STEPS 100

typedef __bf16 bf16x8 __attribute__((ext_vector_type(8)));
typedef float f32x16 __attribute__((ext_vector_type(16)));

__device__ __forceinline__ float sigf(float x) { return 1.0f / (1.0f + __expf(-x)); }
// tanh(x) = 1 - 2/(1+exp(2x)); saturates correctly at +/-inf
__device__ __forceinline__ float tanh_fast(float x) { return 1.0f - 2.0f / (1.0f + __expf(2.0f * x)); }

// global->LDS async copy, 16B/lane; dst = wave-uniform base, HW scatters lane i to dst+16i.
__device__ __forceinline__ void load_lds16(const void* g, void* l) {
    __builtin_amdgcn_global_load_lds((const __attribute__((address_space(1))) void*)g,
                                     (__attribute__((address_space(3))) void*)l, 16, 0, 0);
}

// ---------------- fold: wcomb = Whh + Wih@Wout (fp32), bias1 = b_lstm + Wih@b_out ----------------
// Exact algebra: inp_t = out_{t-1} = h_t@Wout^T + b_out  (h_t = h entering step t), so for t>=1
//   gates_t = inp_t@Wih^T + h_t@Whh^T + b_lstm = h_t @ (Whh + Wih@Wout)^T + (b_lstm + Wih@b_out).
// t=0 keeps plain Whh/b_lstm (inp_0 = 0).
__global__ __launch_bounds__(64) void fold_weights(
    const float* __restrict__ Wih, const float* __restrict__ Whh,
    const float* __restrict__ Wout, const float* __restrict__ b_lstm,
    const float* __restrict__ b_out, float* __restrict__ wcomb, float* __restrict__ bias1) {
    __shared__ float wrow[64];
    const int n = blockIdx.x;           // 2048 blocks: one gate-row each
    const int tid = threadIdx.x;
    wrow[tid] = Wih[n * 64 + tid];
    __syncthreads();
    for (int k = tid; k < HIDDEN; k += 64) {
        float s = Whh[n * HIDDEN + k];
#pragma unroll 16
        for (int o = 0; o < 64; ++o) s += wrow[o] * Wout[o * HIDDEN + k];
        wcomb[n * HIDDEN + k] = s;
    }
    if (tid == 0) {
        float s = b_lstm[n];
        for (int o = 0; o < 64; ++o) s += wrow[o] * b_out[o];
        bias1[n] = s;
    }
}

// ---------------- pack (fp32 -> bf16) into swizzled fragment-ordered layout ----------------
// P layout: [16 cb][8 ck][128 row][64 e'] bf16;  row = g*32+cc -> n = g*512 + cb*32 + cc;
// content at e' is logical k = ck*64 + (e' ^ ((row&7)<<3))  (inverse-swz source + swz on read).
__global__ void pack_weights(const float* __restrict__ Whh, const float* __restrict__ wcomb,
                             const float* __restrict__ Wout,
                             __bf16* __restrict__ P0, __bf16* __restrict__ P1,
                             __bf16* __restrict__ wout) {
    const int NP = 16 * 8 * 128 * 64;   // 1048576
    for (int idx = blockIdx.x * 256 + threadIdx.x; idx < NP; idx += gridDim.x * 256) {
        int e_p = idx & 63;
        int row = (idx >> 6) & 127;
        int ck  = (idx >> 13) & 7;
        int cb  = idx >> 16;
        int k = ck * 64 + (e_p ^ ((row & 7) << 3));
        int n = ((row >> 5) << 9) + (cb << 5) + (row & 31);
        P0[idx] = (__bf16)Whh[n * HIDDEN + k];
        P1[idx] = (__bf16)wcomb[n * HIDDEN + k];
    }
    for (int idx = blockIdx.x * 256 + threadIdx.x; idx < OUTPUT * HIDDEN; idx += gridDim.x * 256)
        wout[idx] = (__bf16)Wout[idx];
}

// ---------------- state init ----------------
__global__ void init_state(const float* __restrict__ h0, const float* __restrict__ c0,
                           __bf16* __restrict__ h, float* __restrict__ c) {
    int idx = blockIdx.x * 256 + threadIdx.x;
    if (idx < BATCH * HIDDEN) {
        int j = idx & (HIDDEN - 1);
        h[idx] = (__bf16)h0[j];
        c[idx] = c0[j];
    }
}

// ---------------- fused gates GEMM + LSTM cell update (R5-proven structure, K=512) ----------------
// gates = h @ P^T + bias  (M=8192, N=4*512, K=512 = 8 chunks of 64)
// Block: 4 waves on M. Tile 256 rows x 32 cols x 4 gates. B staged in LDS (dbuf 2x16KB)
// via global_load_lds from pre-swizzled pack; A (h rows) direct global (L1-cached).
// XCD slice: XCD x owns rows [1024x, 1024x+1024) x all 16 col-blocks.
__global__ __launch_bounds__(256, 2) void lstm_step(
    const __bf16* __restrict__ h_in, const __bf16* __restrict__ P,
    const float* __restrict__ bias,
    float* __restrict__ c, __bf16* __restrict__ h_out) {

    __shared__ __bf16 bsm[2][128][64];  // 32 KB

    const int lane = threadIdx.x & 63;
    const int wave = threadIdx.x >> 6;
    const int r = lane & 31;
    const int koff = (lane >> 5) * 8;

    const int bid = blockIdx.x;          // 512 blocks, 8 | 512 -> bijective xcd slice
    const int j = bid >> 3;
    const int rb = ((bid & 7) << 2) | (j & 3);   // row-block 0..31
    const int cb = j >> 2;                        // col-block 0..15

    const int mBase = rb * 256 + wave * 64;
    const int ncol = cb * 32 + r;
    const int arow = mBase + r;

    f32x16 acc[4][2];
#pragma unroll
    for (int g = 0; g < 4; ++g)
#pragma unroll
        for (int m = 0; m < 2; ++m)
#pragma unroll
            for (int v = 0; v < 16; ++v) acc[g][m][v] = 0.0f;

    // stage chunk ck into bsm[buf]: 16KB, 4 waves x 4 instrs x 1KB, coalesced
    auto stage = [&](int ck, int buf) {
        const char* src = (const char*)P + (((size_t)(cb * 8 + ck)) << 14)
                          + ((size_t)(wave * 4) << 10) + lane * 16;
        char* dst = (char*)&bsm[buf][0][0] + ((size_t)(wave * 4) << 10);
#pragma unroll
        for (int i = 0; i < 4; ++i)
            load_lds16(src + i * 1024, dst + i * 1024);
    };

    stage(0, 0);
    __syncthreads();   // drains vmcnt(0): chunk 0 resident

    int buf = 0;
    for (int ck = 0; ck < 8; ++ck) {
        if (ck < 7) stage(ck + 1, buf ^ 1);   // prefetch overlaps this chunk's MFMAs

        const __bf16* ap = h_in + arow * HIDDEN + ck * 64;
        const __bf16* bb = &bsm[buf][0][0];
#pragma unroll
        for (int kk = 0; kk < 4; ++kk) {
            bf16x8 a0 = *reinterpret_cast<const bf16x8*>(ap + kk * 16 + koff);
            bf16x8 a1 = *reinterpret_cast<const bf16x8*>(ap + 32 * HIDDEN + kk * 16 + koff);
            const int eo = (kk * 16 + koff) ^ ((r & 7) << 3);   // read-side XOR
#pragma unroll
            for (int g = 0; g < 4; ++g) {
                bf16x8 b = *reinterpret_cast<const bf16x8*>(bb + (g * 32 + r) * 64 + eo);
                acc[g][0] = __builtin_amdgcn_mfma_f32_32x32x16_bf16(a0, b, acc[g][0], 0, 0, 0);
                acc[g][1] = __builtin_amdgcn_mfma_f32_32x32x16_bf16(a1, b, acc[g][1], 0, 0, 0);
            }
        }
        __syncthreads();  // reads of buf done + staged chunk landed before overwrite
        buf ^= 1;
    }

    // cell epilogue: C/D map col=lane&31, row=(v&3)+8*(v>>2)+4*(lane>>5)
    const float bi = bias[0 * HIDDEN + ncol];
    const float bf = bias[1 * HIDDEN + ncol];
    const float bg = bias[2 * HIDDEN + ncol];
    const float bo = bias[3 * HIDDEN + ncol];
    const int rbase = 4 * (lane >> 5);
#pragma unroll
    for (int m = 0; m < 2; ++m) {
#pragma unroll
        for (int v = 0; v < 16; ++v) {
            int row = mBase + m * 32 + (v & 3) + 8 * (v >> 2) + rbase;
            float iv = sigf(acc[0][m][v] + bi);
            float fv = sigf(acc[1][m][v] + bf);
            float gv = tanh_fast(acc[2][m][v] + bg);
            float ov = sigf(acc[3][m][v] + bo);
            float cold = c[row * HIDDEN + ncol];
            float cnew = fv * cold + iv * gv;
            c[row * HIDDEN + ncol] = cnew;   // fp32 cell state
            h_out[row * HIDDEN + ncol] = (__bf16)(ov * tanh_fast(cnew));
        }
    }
}

// ---------------- output GEMM: out_t = h_next @ Wout^T + b_out ----------------
// Off the recurrence critical path now (nothing downstream reads out). 256 blocks x 2 waves.
__global__ __launch_bounds__(128, 2) void out_step(
    const __bf16* __restrict__ h, const __bf16* __restrict__ wout,
    const float* __restrict__ b_out, float* __restrict__ out, int t) {

    const int lane = threadIdx.x & 63;
    const int wave = threadIdx.x >> 6;
    const int r = lane & 31;
    const int koff = (lane >> 5) * 8;

    const int bid = blockIdx.x;
    const int mBase = ((bid & 7) << 10) + ((bid >> 3) << 5);  // xcd*1024 + j*32 (same slab as gates)
    const int nBase = wave * 32;

    f32x16 acc;
#pragma unroll
    for (int v = 0; v < 16; ++v) acc[v] = 0.0f;

    const __bf16* ap = h + (mBase + r) * HIDDEN + koff;
    const __bf16* bp = wout + (nBase + r) * HIDDEN + koff;
#pragma unroll 8
    for (int kk = 0; kk < HIDDEN / 16; ++kk) {
        bf16x8 a = *reinterpret_cast<const bf16x8*>(ap + kk * 16);
        bf16x8 b = *reinterpret_cast<const bf16x8*>(bp + kk * 16);
        acc = __builtin_amdgcn_mfma_f32_32x32x16_bf16(a, b, acc, 0, 0, 0);
    }

    const int col = nBase + r;
    const float bv = b_out[col];
    const int rbase = 4 * (lane >> 5);
#pragma unroll
    for (int v = 0; v < 16; ++v) {
        int row = mBase + (v & 3) + 8 * (v >> 2) + rbase;
        out[row * (STEPS * OUTPUT) + t * OUTPUT + col] = acc[v] + bv;   // (B, steps, O) fp32
    }
}

extern "C" void kernel_launch(void* const* d_in, const int* in_sizes, int n_in,
                              void* d_out, int out_size, void* d_ws, size_t ws_size,
                              hipStream_t stream) {
    // inputs: x(unused), W_ih, W_hh, b_lstm, h0, c0, W_out, b_out, steps
    const float* W_ih   = (const float*)d_in[1];
    const float* W_hh   = (const float*)d_in[2];
    const float* b_lstm = (const float*)d_in[3];
    const float* h0     = (const float*)d_in[4];
    const float* c0     = (const float*)d_in[5];
    const float* W_out  = (const float*)d_in[6];
    const float* b_out  = (const float*)d_in[7];
    float* out = (float*)d_out;

    char* ws = (char*)d_ws;
    size_t off = 0;
    auto alloc = [&](size_t bytes) -> void* {
        void* p = ws + off;
        off += (bytes + 255) & ~(size_t)255;
        return p;
    };
    float*  wcomb = (float*)alloc((size_t)4 * HIDDEN * HIDDEN * 4);   // 4 MB fp32
    float*  bias1 = (float*)alloc((size_t)4 * HIDDEN * 4);
    __bf16* P0    = (__bf16*)alloc((size_t)16 * 8 * 128 * 64 * 2);    // 2 MB
    __bf16* P1    = (__bf16*)alloc((size_t)16 * 8 * 128 * 64 * 2);    // 2 MB
    __bf16* wout  = (__bf16*)alloc((size_t)OUTPUT * HIDDEN * 2);
    __bf16* hA    = (__bf16*)alloc((size_t)BATCH * HIDDEN * 2);
    __bf16* hB    = (__bf16*)alloc((size_t)BATCH * HIDDEN * 2);
    float*  c     = (float*)alloc((size_t)BATCH * HIDDEN * 4);

    fold_weights<<<4 * HIDDEN, 64, 0, stream>>>(W_ih, W_hh, W_out, b_lstm, b_out, wcomb, bias1);
    pack_weights<<<2048, 256, 0, stream>>>(W_hh, wcomb, W_out, P0, P1, wout);
    init_state<<<(BATCH * HIDDEN + 255) / 256, 256, 0, stream>>>(h0, c0, hA, c);

    __bf16* hc = hA;
    __bf16* hn = hB;
    for (int t = 0; t < STEPS; ++t) {
        const __bf16* P    = (t == 0) ? P0 : P1;
        const float*  bias = (t == 0) ? b_lstm : bias1;
        lstm_step<<<512, 256, 0, stream>>>(hc, P, bias, c, hn);
        out_step<<<BATCH / 32, 128, 0, stream>>>(hn, wout, b_out, out, t);
        __bf16* tmp = hc; hc = hn; hn = tmp;  // double-buffer h
    }
}